// Round 3
// baseline (158.049 us; speedup 1.0000x reference)
//
#include <hip/hip_runtime.h>
#include <stdint.h>

#define N_TOK 8192
#define DIN   1024
#define DOUT  1024
#define NG    8
#define LSCALE 2.0f

typedef __attribute__((ext_vector_type(4))) float  float4v;
typedef __attribute__((ext_vector_type(8))) short  short8;
typedef short8  frag_ab;   // 8 bf16
typedef float4v frag_cd;   // 4 fp32

__device__ __forceinline__ short f2bf(float f) {
    union { float f; uint32_t u; } v; v.f = f;
    uint32_t r = v.u + 0x7fffu + ((v.u >> 16) & 1u);  // RNE
    return (short)(r >> 16);
}

__device__ __forceinline__ void load_lds16(const void* g, void* lds) {
    __builtin_amdgcn_global_load_lds(
        (const __attribute__((address_space(1))) uint32_t*)g,
        (__attribute__((address_space(3))) uint32_t*)lds,
        16, 0, 0);
}

// ============ prep_w: (W + 2*A@B)^T into Wt | starts ============
// x-conversion is fused into the GEMM (reg-staged); prep only merges weights.
#define PREPW_GRID 2081

__global__ __launch_bounds__(256) void prep_w(
        const float* __restrict__ Wb, const float* __restrict__ WA,
        const float* __restrict__ WB, const int* __restrict__ groups,
        short* __restrict__ Wt, int* __restrict__ starts) {
    __shared__ float tile[64][65];   // W[k][n] 64x64 tile
    __shared__ float At[64][17];     // A[k][r]  64x16 tile
    __shared__ float Bt[16][64];     // B[r][n]  16x64 tile
    const int blk = blockIdx.x, t = threadIdx.x;

    if (blk < 2048) {                       // ---- W' = W + 2*A@B, transposed -> Wt
        int g = blk >> 8, rem = blk & 255;
        int n0 = (rem & 15) * 64, k0 = (rem >> 4) * 64;
        const float* Wg = Wb + (size_t)g * DIN * DOUT;
#pragma unroll
        for (int i = 0; i < 4; ++i) {
            int idx = i * 256 + t;
            int r = idx >> 4, c = (idx & 15) * 4;
            float4v v = *(const float4v*)(Wg + (size_t)(k0 + r) * DOUT + n0 + c);
            tile[r][c+0]=v[0]; tile[r][c+1]=v[1]; tile[r][c+2]=v[2]; tile[r][c+3]=v[3];
        }
        {   // A tile: At[kk][r] = WA[g][k0+kk][r]
            int kk = t >> 2, c = (t & 3) * 4;
            float4v v = *(const float4v*)(WA + ((size_t)g * DIN + k0 + kk) * 16 + c);
            At[kk][c+0]=v[0]; At[kk][c+1]=v[1]; At[kk][c+2]=v[2]; At[kk][c+3]=v[3];
        }
        {   // B tile: Bt[r][n] = WB[g][r][n0+n]
            int r = t >> 4, c = (t & 15) * 4;
            float4v v = *(const float4v*)(WB + ((size_t)g * 16 + r) * DOUT + n0 + c);
            Bt[r][c+0]=v[0]; Bt[r][c+1]=v[1]; Bt[r][c+2]=v[2]; Bt[r][c+3]=v[3];
        }
        __syncthreads();
        short* Wtg = Wt + (size_t)g * DOUT * DIN;
#pragma unroll
        for (int i = 0; i < 2; ++i) {
            int idx = i * 256 + t;
            int n = idx >> 3, c8 = (idx & 7) * 8;
            float corr[8] = {0.f,0.f,0.f,0.f,0.f,0.f,0.f,0.f};
#pragma unroll
            for (int r = 0; r < 16; ++r) {
                float bv = Bt[r][n];
#pragma unroll
                for (int j = 0; j < 8; ++j) corr[j] += At[c8 + j][r] * bv;
            }
            short8 o;
#pragma unroll
            for (int j = 0; j < 8; ++j)
                o[j] = f2bf(tile[c8 + j][n] + LSCALE * corr[j]);
            *(short8*)(Wtg + (size_t)(n0 + n) * DIN + k0 + c8) = o;
        }
    } else {                                // ---- starts from sorted groups
        int i = (blk - 2048) * 256 + t;
        if (i > N_TOK) return;
        int cur  = (i < N_TOK) ? groups[i] : NG;
        int prev = (i == 0) ? -1 : groups[i - 1];
        for (int g = prev + 1; g <= cur; ++g) starts[g] = i;
    }
}

// ============ grouped GEMM: group-aligned 128x128 tiles, BK=64, dbuf ============
// A-side: fp32 x reg-staged (load-early / cvt+ds_write-late, T14) -> no xb pass.
// B-side: merged W'^T bf16 via global_load_lds with inverse-swizzled source.
#define BM 128
#define BN 128
#define BK 64
#define NKT (DIN / BK)        // 16
#define MAXRT (N_TOK / BM + NG - 1)   // 71 row-tiles max
#define GRID  (MAXRT * (DOUT / BN))   // 568 (divisible by 8)

__global__ __launch_bounds__(256, 2)
void gemm_grouped(const float* __restrict__ x,    // [N][DIN] fp32
                  const short* __restrict__ Wt,   // [G][DOUT][DIN] bf16 (merged W'^T)
                  const int*   __restrict__ starts,
                  float* __restrict__ out) {
    __shared__ short As[2][BM * BK];   // 2 x 16 KB
    __shared__ short Bs[2][BN * BK];   // 2 x 16 KB  (total 64 KB -> 2 blocks/CU)

    const int t    = threadIdx.x;
    const int lane = t & 63;
    const int wid  = t >> 6;
    // XCD-aware remap: xcd = L&7 owns a contiguous chunk of 71 (rt,ct) pairs
    const int L  = blockIdx.x;               // 0..567
    const int wg = (L & 7) * MAXRT + (L >> 3);
    const int rt = wg >> 3;                  // row-tile 0..70
    const int ct = wg & 7;                   // col-tile 0..7
    const int col0 = ct * BN;

    // ---- map rt -> (group, row0) via group-aligned uniform tiling ----
    int g = -1, row0 = 0, rhi = 0;
    {
        int accum = 0;
#pragma unroll
        for (int gg = 0; gg < NG; ++gg) {
            int s0 = starts[gg], s1 = starts[gg + 1];
            int nt = (s1 - s0 + BM - 1) >> 7;          // tiles in this group
            if (g < 0 && rt < accum + nt) {
                g = gg;
                row0 = s0 + (rt - accum) * BM;
                rhi = (s1 < row0 + BM) ? s1 : row0 + BM;
            }
            accum += nt;
        }
    }
    if (g < 0) return;   // past the last real tile (uniform per block)

    const short* wgp = Wt + (size_t)g * DOUT * DIN;
    const int wr  = (wid >> 1) * 64;
    const int wc  = (wid & 1) * 64;
    const int m16 = lane & 15;
    const int q   = lane >> 4;
    const int phase = ((L >> 3) & 1) * 8;    // stagger K-ring between co-resident blocks

    frag_cd acc[4][4];
#pragma unroll
    for (int i = 0; i < 4; ++i)
#pragma unroll
        for (int j = 0; j < 4; ++j) { frag_cd z = {0.f,0.f,0.f,0.f}; acc[i][j] = z; }

    // ---- A: fp32 loads into regs (issue early), cvt+ds_write (late) ----
    float4v ar[8];
    auto LOAD_A = [&](int kt) {
#pragma unroll
        for (int i = 0; i < 4; ++i) {
            int Lc = i * 256 + t;            // chunk 0..1023
            int r  = Lc >> 3;                // row 0..127
            int c8 = Lc & 7;                 // linear k-chunk (swizzle applied on write)
            int rg = row0 + r; rg = rg < N_TOK ? rg : N_TOK - 1;   // clamp OOB partials
            const float4v* p = (const float4v*)(x + (size_t)rg * DIN + kt + c8 * 8);
            ar[2*i]   = p[0];
            ar[2*i+1] = p[1];
        }
    };
    auto CVT_A = [&](int buf) {
#pragma unroll
        for (int i = 0; i < 4; ++i) {
            int Lc = i * 256 + t;
            int r  = Lc >> 3;
            int c8 = Lc & 7;
            float4v a = ar[2*i], b = ar[2*i+1];
            short8 o;
            o[0]=f2bf(a[0]); o[1]=f2bf(a[1]); o[2]=f2bf(a[2]); o[3]=f2bf(a[3]);
            o[4]=f2bf(b[0]); o[5]=f2bf(b[1]); o[6]=f2bf(b[2]); o[7]=f2bf(b[3]);
            *(short8*)&As[buf][r * BK + ((c8 ^ (r & 7)) << 3)] = o;
        }
    };
    auto STAGE_B = [&](int buf, int kt) {
#pragma unroll
        for (int i = 0; i < 4; ++i) {
            int Lc = i * 256 + t;
            int r  = Lc >> 3;
            int c8 = (Lc & 7) ^ (r & 7);     // inverse-swizzled source, linear dest
            load_lds16(wgp + (size_t)(col0 + r) * DIN + kt + c8 * 8,
                       &Bs[buf][(i * 256 + wid * 64) * 8]);
        }
    };

    // prologue: fill buffer 0
    {
        int kt0 = (phase & (NKT - 1)) * BK;
        LOAD_A(kt0);
        STAGE_B(0, kt0);
        CVT_A(0);
    }
    __syncthreads();          // drains vmcnt+lgkm: buf0 ready

    int cur = 0;
#pragma unroll 2
    for (int kt_ii = 0; kt_ii < NKT; ++kt_ii) {
        const bool hasnext = (kt_ii + 1 < NKT);
        if (hasnext) {
            int ktn = ((kt_ii + 1 + phase) & (NKT - 1)) * BK;
            LOAD_A(ktn);                 // issue fp32 x loads (results used post-compute)
            STAGE_B(cur ^ 1, ktn);       // issue B global->LDS DMA
        }

        // compute from buf[cur] while next-tile loads are in flight
#pragma unroll
        for (int kk = 0; kk < BK; kk += 32) {
            frag_ab af[4], bf[4];
            const int ch = (kk >> 3) + q;            // 0..7
#pragma unroll
            for (int mi = 0; mi < 4; ++mi) {
                int rr = wr + mi * 16 + m16;
                af[mi] = *(const frag_ab*)&As[cur][rr * BK + ((ch ^ (rr & 7)) << 3)];
            }
#pragma unroll
            for (int ni = 0; ni < 4; ++ni) {
                int cc = wc + ni * 16 + m16;
                bf[ni] = *(const frag_ab*)&Bs[cur][cc * BK + ((ch ^ (cc & 7)) << 3)];
            }
#pragma unroll
            for (int mi = 0; mi < 4; ++mi)
#pragma unroll
                for (int ni = 0; ni < 4; ++ni)
                    acc[mi][ni] = __builtin_amdgcn_mfma_f32_16x16x32_bf16(
                        af[mi], bf[ni], acc[mi][ni], 0, 0, 0);
        }

        if (hasnext) CVT_A(cur ^ 1);     // write-late: vmcnt waits land after MFMAs

        __syncthreads();      // next buffer ready, cur reads done
        cur ^= 1;
    }

    // ---- masked store: C/D layout col = lane&15, row = q*4 + reg ----
#pragma unroll
    for (int mi = 0; mi < 4; ++mi)
#pragma unroll
        for (int r = 0; r < 4; ++r) {
            int grow = row0 + wr + mi * 16 + q * 4 + r;
            if (grow < rhi) {
                float* orow = out + (size_t)grow * DOUT + col0 + wc + m16;
#pragma unroll
                for (int ni = 0; ni < 4; ++ni) orow[ni * 16] = acc[mi][ni][r];
            }
        }
}

extern "C" void kernel_launch(void* const* d_in, const int* in_sizes, int n_in,
                              void* d_out, int out_size, void* d_ws, size_t ws_size,
                              hipStream_t stream) {
    const float* x      = (const float*)d_in[0];
    const int*   groups = (const int*)d_in[1];
    const float* Wb     = (const float*)d_in[2];
    const float* WA     = (const float*)d_in[3];
    const float* WB     = (const float*)d_in[4];
    float* out = (float*)d_out;

    char* ws = (char*)d_ws;
    int*   starts = (int*)ws;                                             // 36 B
    short* Wt     = (short*)(ws + 1024);                                  // 16 MB

    hipLaunchKernelGGL(prep_w, dim3(PREPW_GRID), dim3(256), 0, stream,
                       Wb, WA, WB, groups, Wt, starts);
    hipLaunchKernelGGL(gemm_grouped, dim3(GRID), dim3(256), 0, stream,
                       x, Wt, starts, out);
}

// Round 4
// 155.076 us; speedup vs baseline: 1.0192x; 1.0192x over previous
//
#include <hip/hip_runtime.h>
#include <stdint.h>

#define N_TOK 8192
#define DIN   1024
#define DOUT  1024
#define NG    8
#define LSCALE 2.0f

typedef __attribute__((ext_vector_type(4))) float  float4v;
typedef __attribute__((ext_vector_type(8))) short  short8;
typedef short8  frag_ab;   // 8 bf16
typedef float4v frag_cd;   // 4 fp32

__device__ __forceinline__ short f2bf(float f) {
    union { float f; uint32_t u; } v; v.f = f;
    uint32_t r = v.u + 0x7fffu + ((v.u >> 16) & 1u);  // RNE
    return (short)(r >> 16);
}

__device__ __forceinline__ void load_lds16(const void* g, void* lds) {
    __builtin_amdgcn_global_load_lds(
        (const __attribute__((address_space(1))) uint32_t*)g,
        (__attribute__((address_space(3))) uint32_t*)lds,
        16, 0, 0);
}

// ============ fused prep: cvt_x | (W + 2*A@B)^T into Wt | starts ============
// Weight-merge: out = x @ (W_base + SCALE * W_A @ W_B)  — fold LoRA into W'
// so the hot GEMM is a single clean grouped GEMM.
#define PREP_GRID 6177

__global__ __launch_bounds__(256) void prep_kernel(
        const float* __restrict__ x, const float* __restrict__ Wb,
        const float* __restrict__ WA, const float* __restrict__ WB,
        const int* __restrict__ groups,
        short* __restrict__ xb, short* __restrict__ Wt,
        int* __restrict__ starts) {
    __shared__ float tile[64][65];   // W[k][n] 64x64 tile
    __shared__ float At[64][17];     // A[k][r]  64x16 tile
    __shared__ float Bt[16][64];     // B[r][n]  16x64 tile
    const int blk = blockIdx.x, t = threadIdx.x;

    if (blk < 4096) {                       // ---- x fp32 -> bf16
        size_t idx = (size_t)(blk * 256 + t) * 8;
        const float4v* p = (const float4v*)(x + idx);
        float4v a = p[0], b = p[1];
        short8 o;
        o[0]=f2bf(a[0]); o[1]=f2bf(a[1]); o[2]=f2bf(a[2]); o[3]=f2bf(a[3]);
        o[4]=f2bf(b[0]); o[5]=f2bf(b[1]); o[6]=f2bf(b[2]); o[7]=f2bf(b[3]);
        *(short8*)(xb + idx) = o;
    } else if (blk < 6144) {                // ---- W' = W + 2*A@B, transposed -> Wt
        int b = blk - 4096;
        int g = b >> 8, rem = b & 255;
        int n0 = (rem & 15) * 64, k0 = (rem >> 4) * 64;
        const float* Wg = Wb + (size_t)g * DIN * DOUT;
#pragma unroll
        for (int i = 0; i < 4; ++i) {
            int idx = i * 256 + t;
            int r = idx >> 4, c = (idx & 15) * 4;
            float4v v = *(const float4v*)(Wg + (size_t)(k0 + r) * DOUT + n0 + c);
            tile[r][c+0]=v[0]; tile[r][c+1]=v[1]; tile[r][c+2]=v[2]; tile[r][c+3]=v[3];
        }
        {   // A tile: At[kk][r] = WA[g][k0+kk][r]
            int kk = t >> 2, c = (t & 3) * 4;
            float4v v = *(const float4v*)(WA + ((size_t)g * DIN + k0 + kk) * 16 + c);
            At[kk][c+0]=v[0]; At[kk][c+1]=v[1]; At[kk][c+2]=v[2]; At[kk][c+3]=v[3];
        }
        {   // B tile: Bt[r][n] = WB[g][r][n0+n]
            int r = t >> 4, c = (t & 15) * 4;
            float4v v = *(const float4v*)(WB + ((size_t)g * 16 + r) * DOUT + n0 + c);
            Bt[r][c+0]=v[0]; Bt[r][c+1]=v[1]; Bt[r][c+2]=v[2]; Bt[r][c+3]=v[3];
        }
        __syncthreads();
        short* Wtg = Wt + (size_t)g * DOUT * DIN;
#pragma unroll
        for (int i = 0; i < 2; ++i) {
            int idx = i * 256 + t;
            int n = idx >> 3, c8 = (idx & 7) * 8;
            float corr[8] = {0.f,0.f,0.f,0.f,0.f,0.f,0.f,0.f};
#pragma unroll
            for (int r = 0; r < 16; ++r) {
                float bv = Bt[r][n];
#pragma unroll
                for (int j = 0; j < 8; ++j) corr[j] += At[c8 + j][r] * bv;
            }
            short8 o;
#pragma unroll
            for (int j = 0; j < 8; ++j)
                o[j] = f2bf(tile[c8 + j][n] + LSCALE * corr[j]);
            *(short8*)(Wtg + (size_t)(n0 + n) * DIN + k0 + c8) = o;
        }
    } else {                                // ---- starts from sorted groups
        int i = (blk - 6144) * 256 + t;
        if (i > N_TOK) return;
        int cur  = (i < N_TOK) ? groups[i] : NG;
        int prev = (i == 0) ? -1 : groups[i - 1];
        for (int g = prev + 1; g <= cur; ++g) starts[g] = i;
    }
}

// ============ grouped GEMM: uniform group-aligned 128x128 tiles, BK=64, dbuf ============
// Tiles are aligned to group starts: every tile's rows lie in exactly ONE group
// (partial last tile per group, stores masked). Double-buffered LDS (2x32KB=64KB,
// 2 blocks/CU) with STAGE(t+1) issued before compute(t): T3-minimum 2-phase.
// Both operands staged via global_load_lds (linear dest + inverse-swizzled source);
// reg-staged A (T14) was measured net-negative here (round 3: gemm 38->51.5us).
#define BM 128
#define BN 128
#define BK 64
#define NKT (DIN / BK)        // 16
#define MAXRT (N_TOK / BM + NG - 1)   // 71 row-tiles max
#define GRID  (MAXRT * (DOUT / BN))   // 568 (divisible by 8)

__global__ __launch_bounds__(256, 2)
void gemm_grouped(const short* __restrict__ xb,   // [N][DIN] bf16
                  const short* __restrict__ Wt,   // [G][DOUT][DIN] bf16 (merged W'^T)
                  const int*   __restrict__ starts,
                  float* __restrict__ out) {
    __shared__ short As[2][BM * BK];   // 2 x 16 KB
    __shared__ short Bs[2][BN * BK];   // 2 x 16 KB  (total 64 KB -> 2 blocks/CU)

    const int t    = threadIdx.x;
    const int lane = t & 63;
    const int wid  = t >> 6;
    // XCD-aware remap: xcd = L&7 owns a contiguous chunk of 71 (rt,ct) pairs;
    // within a chunk ct sweeps fastest -> x row-panel stays L2-hot on its XCD.
    const int L  = blockIdx.x;               // 0..567
    const int wg = (L & 7) * MAXRT + (L >> 3);
    const int rt = wg >> 3;                  // row-tile 0..70
    const int ct = wg & 7;                   // col-tile 0..7
    const int col0 = ct * BN;

    // ---- map rt -> (group, row0) via group-aligned uniform tiling ----
    int g = -1, row0 = 0, rhi = 0;
    {
        int accum = 0;
#pragma unroll
        for (int gg = 0; gg < NG; ++gg) {
            int s0 = starts[gg], s1 = starts[gg + 1];
            int nt = (s1 - s0 + BM - 1) >> 7;          // tiles in this group
            if (g < 0 && rt < accum + nt) {
                g = gg;
                row0 = s0 + (rt - accum) * BM;
                rhi = (s1 < row0 + BM) ? s1 : row0 + BM;
            }
            accum += nt;
        }
    }
    if (g < 0) return;   // past the last real tile (uniform per block)

    const short* wgp = Wt + (size_t)g * DOUT * DIN;
    const int wr  = (wid >> 1) * 64;
    const int wc  = (wid & 1) * 64;
    const int m16 = lane & 15;
    const int q   = lane >> 4;
    const int phase = ((L >> 3) & 1) * 8;    // stagger K-ring between co-resident blocks

    frag_cd acc[4][4];
#pragma unroll
    for (int i = 0; i < 4; ++i)
#pragma unroll
        for (int j = 0; j < 4; ++j) { frag_cd z = {0.f,0.f,0.f,0.f}; acc[i][j] = z; }

    // stage one K-tile (A: 128x64, B: 128x64) into buffer `buf`.
    // LDS slot s of row r holds global chunk s^(r&7); dest is linear in lane order.
    auto STAGE = [&](int buf, int kt) {
#pragma unroll
        for (int i = 0; i < 4; ++i) {
            int Lc = i * 256 + t;            // chunk id 0..1023
            int r  = Lc >> 3;
            int c8 = (Lc & 7) ^ (r & 7);
            load_lds16(xb + (size_t)(row0 + r) * DIN + kt + c8 * 8,
                       &As[buf][(i * 256 + wid * 64) * 8]);
        }
#pragma unroll
        for (int i = 0; i < 4; ++i) {
            int Lc = i * 256 + t;
            int r  = Lc >> 3;
            int c8 = (Lc & 7) ^ (r & 7);
            load_lds16(wgp + (size_t)(col0 + r) * DIN + kt + c8 * 8,
                       &Bs[buf][(i * 256 + wid * 64) * 8]);
        }
    };

    // prologue: fill buffer 0
    STAGE(0, ((0 + phase) & (NKT - 1)) * BK);
    __syncthreads();          // drains vmcnt(0): buf0 ready

    int cur = 0;
#pragma unroll 2
    for (int kt_ii = 0; kt_ii < NKT; ++kt_ii) {
        if (kt_ii + 1 < NKT)
            STAGE(cur ^ 1, ((kt_ii + 1 + phase) & (NKT - 1)) * BK);

        // compute from buf[cur] while next-tile loads are in flight
#pragma unroll
        for (int kk = 0; kk < BK; kk += 32) {
            frag_ab af[4], bf[4];
            const int ch = (kk >> 3) + q;            // 0..7
#pragma unroll
            for (int mi = 0; mi < 4; ++mi) {
                int rr = wr + mi * 16 + m16;
                af[mi] = *(const frag_ab*)&As[cur][rr * BK + ((ch ^ (rr & 7)) << 3)];
            }
#pragma unroll
            for (int ni = 0; ni < 4; ++ni) {
                int cc = wc + ni * 16 + m16;
                bf[ni] = *(const frag_ab*)&Bs[cur][cc * BK + ((ch ^ (cc & 7)) << 3)];
            }
#pragma unroll
            for (int mi = 0; mi < 4; ++mi)
#pragma unroll
                for (int ni = 0; ni < 4; ++ni)
                    acc[mi][ni] = __builtin_amdgcn_mfma_f32_16x16x32_bf16(
                        af[mi], bf[ni], acc[mi][ni], 0, 0, 0);
        }

        __syncthreads();      // drains vmcnt+lgkm: next buffer ready, cur reads done
        cur ^= 1;
    }

    // ---- masked store: C/D layout col = lane&15, row = q*4 + reg ----
    // nontemporal: out (32 MB) is never re-read; keep it out of L2 so
    // xb/Wt panels stay resident.
#pragma unroll
    for (int mi = 0; mi < 4; ++mi)
#pragma unroll
        for (int r = 0; r < 4; ++r) {
            int grow = row0 + wr + mi * 16 + q * 4 + r;
            if (grow < rhi) {
                float* orow = out + (size_t)grow * DOUT + col0 + wc + m16;
#pragma unroll
                for (int ni = 0; ni < 4; ++ni)
                    __builtin_nontemporal_store(acc[mi][ni][r], orow + ni * 16);
            }
        }
}

extern "C" void kernel_launch(void* const* d_in, const int* in_sizes, int n_in,
                              void* d_out, int out_size, void* d_ws, size_t ws_size,
                              hipStream_t stream) {
    const float* x      = (const float*)d_in[0];
    const int*   groups = (const int*)d_in[1];
    const float* Wb     = (const float*)d_in[2];
    const float* WA     = (const float*)d_in[3];
    const float* WB     = (const float*)d_in[4];
    float* out = (float*)d_out;

    char* ws = (char*)d_ws;
    int*   starts = (int*)ws;                                             // 36 B
    short* xb     = (short*)(ws + 1024);                                  // 16 MB
    short* Wt     = (short*)(ws + 1024 + (size_t)16 * 1024 * 1024);       // 16 MB

    hipLaunchKernelGGL(prep_kernel, dim3(PREP_GRID), dim3(256), 0, stream,
                       x, Wb, WA, WB, groups, xb, Wt, starts);
    hipLaunchKernelGGL(gemm_grouped, dim3(GRID), dim3(256), 0, stream,
                       xb, Wt, starts, out);
}

// Round 6
// 149.006 us; speedup vs baseline: 1.0607x; 1.0407x over previous
//
#include <hip/hip_runtime.h>
#include <stdint.h>

#define N_TOK 8192
#define DIN   1024
#define DOUT  1024
#define NG    8
#define LSCALE 2.0f

typedef __attribute__((ext_vector_type(4))) float  float4v;
typedef __attribute__((ext_vector_type(8))) short  short8;
typedef short8  frag_ab;   // 8 bf16
typedef float4v frag_cd;   // 4 fp32

__device__ __forceinline__ short f2bf(float f) {
    union { float f; uint32_t u; } v; v.f = f;
    uint32_t r = v.u + 0x7fffu + ((v.u >> 16) & 1u);  // RNE
    return (short)(r >> 16);
}

__device__ __forceinline__ void load_lds16(const void* g, void* lds) {
    __builtin_amdgcn_global_load_lds(
        (const __attribute__((address_space(1))) uint32_t*)g,
        (__attribute__((address_space(3))) uint32_t*)lds,
        16, 0, 0);
}

// ============ fused prep: cvt_x | (W + 2*A@B)^T into Wt | starts ============
// Weight-merge: out = x @ (W_base + SCALE * W_A @ W_B)  — fold LoRA into W'
// so the hot GEMM is a single clean grouped GEMM.
#define PREP_GRID 6177

__global__ __launch_bounds__(256) void prep_kernel(
        const float* __restrict__ x, const float* __restrict__ Wb,
        const float* __restrict__ WA, const float* __restrict__ WB,
        const int* __restrict__ groups,
        short* __restrict__ xb, short* __restrict__ Wt,
        int* __restrict__ starts) {
    __shared__ float tile[64][65];   // W[k][n] 64x64 tile
    __shared__ float At[64][17];     // A[k][r]  64x16 tile
    __shared__ float Bt[16][64];     // B[r][n]  16x64 tile
    const int blk = blockIdx.x, t = threadIdx.x;

    if (blk < 4096) {                       // ---- x fp32 -> bf16
        size_t idx = (size_t)(blk * 256 + t) * 8;
        const float4v* p = (const float4v*)(x + idx);
        float4v a = p[0], b = p[1];
        short8 o;
        o[0]=f2bf(a[0]); o[1]=f2bf(a[1]); o[2]=f2bf(a[2]); o[3]=f2bf(a[3]);
        o[4]=f2bf(b[0]); o[5]=f2bf(b[1]); o[6]=f2bf(b[2]); o[7]=f2bf(b[3]);
        *(short8*)(xb + idx) = o;
    } else if (blk < 6144) {                // ---- W' = W + 2*A@B, transposed -> Wt
        int b = blk - 4096;
        int g = b >> 8, rem = b & 255;
        int n0 = (rem & 15) * 64, k0 = (rem >> 4) * 64;
        const float* Wg = Wb + (size_t)g * DIN * DOUT;
#pragma unroll
        for (int i = 0; i < 4; ++i) {
            int idx = i * 256 + t;
            int r = idx >> 4, c = (idx & 15) * 4;
            float4v v = *(const float4v*)(Wg + (size_t)(k0 + r) * DOUT + n0 + c);
            tile[r][c+0]=v[0]; tile[r][c+1]=v[1]; tile[r][c+2]=v[2]; tile[r][c+3]=v[3];
        }
        {   // A tile: At[kk][r] = WA[g][k0+kk][r]
            int kk = t >> 2, c = (t & 3) * 4;
            float4v v = *(const float4v*)(WA + ((size_t)g * DIN + k0 + kk) * 16 + c);
            At[kk][c+0]=v[0]; At[kk][c+1]=v[1]; At[kk][c+2]=v[2]; At[kk][c+3]=v[3];
        }
        {   // B tile: Bt[r][n] = WB[g][r][n0+n]
            int r = t >> 4, c = (t & 15) * 4;
            float4v v = *(const float4v*)(WB + ((size_t)g * 16 + r) * DOUT + n0 + c);
            Bt[r][c+0]=v[0]; Bt[r][c+1]=v[1]; Bt[r][c+2]=v[2]; Bt[r][c+3]=v[3];
        }
        __syncthreads();
        short* Wtg = Wt + (size_t)g * DOUT * DIN;
#pragma unroll
        for (int i = 0; i < 2; ++i) {
            int idx = i * 256 + t;
            int n = idx >> 3, c8 = (idx & 7) * 8;
            float corr[8] = {0.f,0.f,0.f,0.f,0.f,0.f,0.f,0.f};
#pragma unroll
            for (int r = 0; r < 16; ++r) {
                float bv = Bt[r][n];
#pragma unroll
                for (int j = 0; j < 8; ++j) corr[j] += At[c8 + j][r] * bv;
            }
            short8 o;
#pragma unroll
            for (int j = 0; j < 8; ++j)
                o[j] = f2bf(tile[c8 + j][n] + LSCALE * corr[j]);
            *(short8*)(Wtg + (size_t)(n0 + n) * DIN + k0 + c8) = o;
        }
    } else {                                // ---- starts from sorted groups
        int i = (blk - 6144) * 256 + t;
        if (i > N_TOK) return;
        int cur  = (i < N_TOK) ? groups[i] : NG;
        int prev = (i == 0) ? -1 : groups[i - 1];
        for (int g = prev + 1; g <= cur; ++g) starts[g] = i;
    }
}

// ============ grouped GEMM: group-aligned 128x128 tiles, BK=64, single-buffer ============
// m97 structure: 32 KB LDS single-buffer -> 4 blocks/CU (launch_bounds(256,4)).
// 1024 slots >= 568 tiles -> single scheduling round (the 2-blocks/CU dbuf
// variant ran 568 tiles in 512 slots = 2 rounds; tail cost ~40%). Explicit
// dbuf measured null vs implicit multi-block overlap (m99/m100/m114).
#define BM 128
#define BN 128
#define BK 64
#define NKT (DIN / BK)        // 16
#define MAXRT (N_TOK / BM + NG - 1)   // 71 row-tiles max
#define GRID  (MAXRT * (DOUT / BN))   // 568 (divisible by 8)

__global__ __launch_bounds__(256, 4)
void gemm_grouped(const short* __restrict__ xb,   // [N][DIN] bf16
                  const short* __restrict__ Wt,   // [G][DOUT][DIN] bf16 (merged W'^T)
                  const int*   __restrict__ starts,
                  float* __restrict__ out) {
    __shared__ short As[BM * BK];   // 16 KB
    __shared__ short Bs[BN * BK];   // 16 KB  (total 32 KB)

    const int t    = threadIdx.x;
    const int lane = t & 63;
    const int wid  = t >> 6;
    // XCD-aware remap: xcd = L&7 owns a contiguous chunk of 71 (rt,ct) pairs;
    // within a chunk ct sweeps fastest -> x row-panel stays L2-hot on its XCD.
    const int L  = blockIdx.x;               // 0..567
    const int wg = (L & 7) * MAXRT + (L >> 3);
    const int rt = wg >> 3;                  // row-tile 0..70
    const int ct = wg & 7;                   // col-tile 0..7
    const int col0 = ct * BN;

    // ---- map rt -> (group, row0) via group-aligned uniform tiling ----
    int g = -1, row0 = 0, rhi = 0;
    {
        int accum = 0;
#pragma unroll
        for (int gg = 0; gg < NG; ++gg) {
            int s0 = starts[gg], s1 = starts[gg + 1];
            int nt = (s1 - s0 + BM - 1) >> 7;          // tiles in this group
            if (g < 0 && rt < accum + nt) {
                g = gg;
                row0 = s0 + (rt - accum) * BM;
                rhi = (s1 < row0 + BM) ? s1 : row0 + BM;
            }
            accum += nt;
        }
    }
    if (g < 0) return;   // past the last real tile (uniform per block)

    const short* wgp = Wt + (size_t)g * DOUT * DIN;
    const int wr  = (wid >> 1) * 64;
    const int wc  = (wid & 1) * 64;
    const int m16 = lane & 15;
    const int q   = lane >> 4;
    const int phase = ((L >> 3) & 3) * 4;    // stagger K-ring between co-resident blocks

    frag_cd acc[4][4];
#pragma unroll
    for (int i = 0; i < 4; ++i)
#pragma unroll
        for (int j = 0; j < 4; ++j) { frag_cd z = {0.f,0.f,0.f,0.f}; acc[i][j] = z; }

    for (int kt_ii = 0; kt_ii < NKT; ++kt_ii) {
        const int kt = ((kt_ii + phase) & (NKT - 1)) * BK;

        // stage A+B: 2x 128 rows x 64 k. LDS slot s of row r holds global
        // chunk s^(r&7); dest linear in lane order (global_load_lds rule).
#pragma unroll
        for (int i = 0; i < 4; ++i) {
            int Lc = i * 256 + t;            // chunk id 0..1023
            int r  = Lc >> 3;
            int c8 = (Lc & 7) ^ (r & 7);
            load_lds16(xb + (size_t)(row0 + r) * DIN + kt + c8 * 8,
                       &As[(i * 256 + wid * 64) * 8]);
        }
#pragma unroll
        for (int i = 0; i < 4; ++i) {
            int Lc = i * 256 + t;
            int r  = Lc >> 3;
            int c8 = (Lc & 7) ^ (r & 7);
            load_lds16(wgp + (size_t)(col0 + r) * DIN + kt + c8 * 8,
                       &Bs[(i * 256 + wid * 64) * 8]);
        }
        __syncthreads();     // drains vmcnt: tile ready

#pragma unroll
        for (int kk = 0; kk < BK; kk += 32) {
            frag_ab af[4], bf[4];
            const int ch = (kk >> 3) + q;            // 0..7
#pragma unroll
            for (int mi = 0; mi < 4; ++mi) {
                int rr = wr + mi * 16 + m16;
                af[mi] = *(const frag_ab*)&As[rr * BK + ((ch ^ (rr & 7)) << 3)];
            }
#pragma unroll
            for (int ni = 0; ni < 4; ++ni) {
                int cc = wc + ni * 16 + m16;
                bf[ni] = *(const frag_ab*)&Bs[cc * BK + ((ch ^ (cc & 7)) << 3)];
            }
#pragma unroll
            for (int mi = 0; mi < 4; ++mi)
#pragma unroll
                for (int ni = 0; ni < 4; ++ni)
                    acc[mi][ni] = __builtin_amdgcn_mfma_f32_16x16x32_bf16(
                        af[mi], bf[ni], acc[mi][ni], 0, 0, 0);
        }

        __syncthreads();     // all reads done before next stage overwrites
    }

    // ---- masked store: C/D layout col = lane&15, row = q*4 + reg ----
    // nontemporal: out (32 MB) never re-read; keep L2 for xb/Wt panels.
#pragma unroll
    for (int mi = 0; mi < 4; ++mi)
#pragma unroll
        for (int r = 0; r < 4; ++r) {
            int grow = row0 + wr + mi * 16 + q * 4 + r;
            if (grow < rhi) {
                float* orow = out + (size_t)grow * DOUT + col0 + wc + m16;
#pragma unroll
                for (int ni = 0; ni < 4; ++ni)
                    __builtin_nontemporal_store(acc[mi][ni][r], orow + ni * 16);
            }
        }
}

extern "C" void kernel_launch(void* const* d_in, const int* in_sizes, int n_in,
                              void* d_out, int out_size, void* d_ws, size_t ws_size,
                              hipStream_t stream) {
    const float* x      = (const float*)d_in[0];
    const int*   groups = (const int*)d_in[1];
    const float* Wb     = (const float*)d_in[2];
    const float* WA     = (const float*)d_in[3];
    const float* WB     = (const float*)d_in[4];
    float* out = (float*)d_out;

    char* ws = (char*)d_ws;
    int*   starts = (int*)ws;                                             // 36 B
    short* xb     = (short*)(ws + 1024);                                  // 16 MB
    short* Wt     = (short*)(ws + 1024 + (size_t)16 * 1024 * 1024);       // 16 MB

    hipLaunchKernelGGL(prep_kernel, dim3(PREP_GRID), dim3(256), 0, stream,
                       x, Wb, WA, WB, groups, xb, Wt, starts);
    hipLaunchKernelGGL(gemm_grouped, dim3(GRID), dim3(256), 0, stream,
                       xb, Wt, starts, out);
}

// Round 7
// 138.896 us; speedup vs baseline: 1.1379x; 1.0728x over previous
//
#include <hip/hip_runtime.h>
#include <stdint.h>

#define N_TOK 8192
#define DIN   1024
#define DOUT  1024
#define NG    8
#define LSCALE 2.0f

typedef __attribute__((ext_vector_type(4))) float  float4v;
typedef __attribute__((ext_vector_type(8))) short  short8;
typedef short8  frag_ab;   // 8 bf16
typedef float4v frag_cd;   // 4 fp32

__device__ __forceinline__ short f2bf(float f) {
    union { float f; uint32_t u; } v; v.f = f;
    uint32_t r = v.u + 0x7fffu + ((v.u >> 16) & 1u);  // RNE
    return (short)(r >> 16);
}

__device__ __forceinline__ void load_lds16(const void* g, void* lds) {
    __builtin_amdgcn_global_load_lds(
        (const __attribute__((address_space(1))) uint32_t*)g,
        (__attribute__((address_space(3))) uint32_t*)lds,
        16, 0, 0);
}

// ============ fused prep: cvt_x | (W + 2*A@B)^T into Wt | starts ============
// Weight-merge: out = x @ (W_base + SCALE * W_A @ W_B)  — fold LoRA into W'
// so the hot GEMM is a single clean grouped GEMM.
// A-tile stored TRANSPOSED (Atr[r][kk]) so the correction's 8 consecutive-kk
// reads vectorize to 2x ds_read_b128 (was 8 scalar stride-17 reads).
#define PREP_GRID 6177

__global__ __launch_bounds__(256) void prep_kernel(
        const float* __restrict__ x, const float* __restrict__ Wb,
        const float* __restrict__ WA, const float* __restrict__ WB,
        const int* __restrict__ groups,
        short* __restrict__ xb, short* __restrict__ Wt,
        int* __restrict__ starts) {
    __shared__ float tile[64][65];   // W[k][n] 64x64 tile
    __shared__ float Atr[16][72];    // A^T tile: Atr[r][kk], 16B-aligned rows
    __shared__ float Bt[16][64];     // B[r][n]  16x64 tile
    const int blk = blockIdx.x, t = threadIdx.x;

    if (blk < 4096) {                       // ---- x fp32 -> bf16
        size_t idx = (size_t)(blk * 256 + t) * 8;
        const float4v* p = (const float4v*)(x + idx);
        float4v a = p[0], b = p[1];
        short8 o;
        o[0]=f2bf(a[0]); o[1]=f2bf(a[1]); o[2]=f2bf(a[2]); o[3]=f2bf(a[3]);
        o[4]=f2bf(b[0]); o[5]=f2bf(b[1]); o[6]=f2bf(b[2]); o[7]=f2bf(b[3]);
        *(short8*)(xb + idx) = o;
    } else if (blk < 6144) {                // ---- W' = W + 2*A@B, transposed -> Wt
        int b = blk - 4096;
        int g = b >> 8, rem = b & 255;
        int n0 = (rem & 15) * 64, k0 = (rem >> 4) * 64;
        const float* Wg = Wb + (size_t)g * DIN * DOUT;
#pragma unroll
        for (int i = 0; i < 4; ++i) {
            int idx = i * 256 + t;
            int r = idx >> 4, c = (idx & 15) * 4;
            float4v v = *(const float4v*)(Wg + (size_t)(k0 + r) * DOUT + n0 + c);
            tile[r][c+0]=v[0]; tile[r][c+1]=v[1]; tile[r][c+2]=v[2]; tile[r][c+3]=v[3];
        }
        {   // A tile, transposed store: Atr[r][kk] = WA[g][k0+kk][r]
            int kk = t >> 2, c = (t & 3) * 4;
            float4v v = *(const float4v*)(WA + ((size_t)g * DIN + k0 + kk) * 16 + c);
            Atr[c+0][kk]=v[0]; Atr[c+1][kk]=v[1]; Atr[c+2][kk]=v[2]; Atr[c+3][kk]=v[3];
        }
        {   // B tile: Bt[r][n] = WB[g][r][n0+n]
            int r = t >> 4, c = (t & 15) * 4;
            float4v v = *(const float4v*)(WB + ((size_t)g * 16 + r) * DOUT + n0 + c);
            Bt[r][c+0]=v[0]; Bt[r][c+1]=v[1]; Bt[r][c+2]=v[2]; Bt[r][c+3]=v[3];
        }
        __syncthreads();
        short* Wtg = Wt + (size_t)g * DOUT * DIN;
#pragma unroll
        for (int i = 0; i < 2; ++i) {
            int idx = i * 256 + t;
            int n = idx >> 3, c8 = (idx & 7) * 8;
            float corr[8] = {0.f,0.f,0.f,0.f,0.f,0.f,0.f,0.f};
#pragma unroll
            for (int r = 0; r < 16; ++r) {
                float bv = Bt[r][n];
                float4v a0 = *(const float4v*)&Atr[r][c8];
                float4v a1 = *(const float4v*)&Atr[r][c8 + 4];
                corr[0] += a0[0] * bv; corr[1] += a0[1] * bv;
                corr[2] += a0[2] * bv; corr[3] += a0[3] * bv;
                corr[4] += a1[0] * bv; corr[5] += a1[1] * bv;
                corr[6] += a1[2] * bv; corr[7] += a1[3] * bv;
            }
            short8 o;
#pragma unroll
            for (int j = 0; j < 8; ++j)
                o[j] = f2bf(tile[c8 + j][n] + LSCALE * corr[j]);
            *(short8*)(Wtg + (size_t)(n0 + n) * DIN + k0 + c8) = o;
        }
    } else {                                // ---- starts from sorted groups
        int i = (blk - 6144) * 256 + t;
        if (i > N_TOK) return;
        int cur  = (i < N_TOK) ? groups[i] : NG;
        int prev = (i == 0) ? -1 : groups[i - 1];
        for (int g = prev + 1; g <= cur; ++g) starts[g] = i;
    }
}

// ============ grouped GEMM: group-aligned 128x128 tiles, BK=64, single-buffer ============
// m97 structure: 32 KB LDS single-buffer -> 4 blocks/CU (launch_bounds(256,4)).
// 1024 slots >= 568 tiles -> single scheduling round (the 2-blocks/CU dbuf
// variant ran 568 tiles in 512 slots = 2 rounds; tail cost ~40%). Explicit
// dbuf measured null vs implicit multi-block overlap (m99/m100/m114).
#define BM 128
#define BN 128
#define BK 64
#define NKT (DIN / BK)        // 16
#define MAXRT (N_TOK / BM + NG - 1)   // 71 row-tiles max
#define GRID  (MAXRT * (DOUT / BN))   // 568 (divisible by 8)

__global__ __launch_bounds__(256, 4)
void gemm_grouped(const short* __restrict__ xb,   // [N][DIN] bf16
                  const short* __restrict__ Wt,   // [G][DOUT][DIN] bf16 (merged W'^T)
                  const int*   __restrict__ starts,
                  float* __restrict__ out) {
    __shared__ short As[BM * BK];   // 16 KB
    __shared__ short Bs[BN * BK];   // 16 KB  (total 32 KB)

    const int t    = threadIdx.x;
    const int lane = t & 63;
    const int wid  = t >> 6;
    // XCD-aware remap: xcd = L&7 owns a contiguous chunk of 71 (rt,ct) pairs;
    // within a chunk ct sweeps fastest -> x row-panel stays L2-hot on its XCD.
    const int L  = blockIdx.x;               // 0..567
    const int wg = (L & 7) * MAXRT + (L >> 3);
    const int rt = wg >> 3;                  // row-tile 0..70
    const int ct = wg & 7;                   // col-tile 0..7
    const int col0 = ct * BN;

    // ---- map rt -> (group, row0) via group-aligned uniform tiling ----
    int g = -1, row0 = 0, rhi = 0;
    {
        int accum = 0;
#pragma unroll
        for (int gg = 0; gg < NG; ++gg) {
            int s0 = starts[gg], s1 = starts[gg + 1];
            int nt = (s1 - s0 + BM - 1) >> 7;          // tiles in this group
            if (g < 0 && rt < accum + nt) {
                g = gg;
                row0 = s0 + (rt - accum) * BM;
                rhi = (s1 < row0 + BM) ? s1 : row0 + BM;
            }
            accum += nt;
        }
    }
    if (g < 0) return;   // past the last real tile (uniform per block)

    const short* wgp = Wt + (size_t)g * DOUT * DIN;
    const int wr  = (wid >> 1) * 64;
    const int wc  = (wid & 1) * 64;
    const int m16 = lane & 15;
    const int q   = lane >> 4;
    const int phase = ((L >> 3) & 3) * 4;    // stagger K-ring between co-resident blocks

    frag_cd acc[4][4];
#pragma unroll
    for (int i = 0; i < 4; ++i)
#pragma unroll
        for (int j = 0; j < 4; ++j) { frag_cd z = {0.f,0.f,0.f,0.f}; acc[i][j] = z; }

    for (int kt_ii = 0; kt_ii < NKT; ++kt_ii) {
        const int kt = ((kt_ii + phase) & (NKT - 1)) * BK;

        // stage A+B: 2x 128 rows x 64 k. LDS slot s of row r holds global
        // chunk s^(r&7); dest linear in lane order (global_load_lds rule).
#pragma unroll
        for (int i = 0; i < 4; ++i) {
            int Lc = i * 256 + t;            // chunk id 0..1023
            int r  = Lc >> 3;
            int c8 = (Lc & 7) ^ (r & 7);
            load_lds16(xb + (size_t)(row0 + r) * DIN + kt + c8 * 8,
                       &As[(i * 256 + wid * 64) * 8]);
        }
#pragma unroll
        for (int i = 0; i < 4; ++i) {
            int Lc = i * 256 + t;
            int r  = Lc >> 3;
            int c8 = (Lc & 7) ^ (r & 7);
            load_lds16(wgp + (size_t)(col0 + r) * DIN + kt + c8 * 8,
                       &Bs[(i * 256 + wid * 64) * 8]);
        }
        __syncthreads();     // drains vmcnt: tile ready

#pragma unroll
        for (int kk = 0; kk < BK; kk += 32) {
            frag_ab af[4], bf[4];
            const int ch = (kk >> 3) + q;            // 0..7
#pragma unroll
            for (int mi = 0; mi < 4; ++mi) {
                int rr = wr + mi * 16 + m16;
                af[mi] = *(const frag_ab*)&As[rr * BK + ((ch ^ (rr & 7)) << 3)];
            }
#pragma unroll
            for (int ni = 0; ni < 4; ++ni) {
                int cc = wc + ni * 16 + m16;
                bf[ni] = *(const frag_ab*)&Bs[cc * BK + ((ch ^ (cc & 7)) << 3)];
            }
#pragma unroll
            for (int mi = 0; mi < 4; ++mi)
#pragma unroll
                for (int ni = 0; ni < 4; ++ni)
                    acc[mi][ni] = __builtin_amdgcn_mfma_f32_16x16x32_bf16(
                        af[mi], bf[ni], acc[mi][ni], 0, 0, 0);
        }

        __syncthreads();     // all reads done before next stage overwrites
    }

    // ---- masked store: C/D layout col = lane&15, row = q*4 + reg ----
    // nontemporal: out (32 MB) never re-read; keep L2 for xb/Wt panels.
#pragma unroll
    for (int mi = 0; mi < 4; ++mi)
#pragma unroll
        for (int r = 0; r < 4; ++r) {
            int grow = row0 + wr + mi * 16 + q * 4 + r;
            if (grow < rhi) {
                float* orow = out + (size_t)grow * DOUT + col0 + wc + m16;
#pragma unroll
                for (int ni = 0; ni < 4; ++ni)
                    __builtin_nontemporal_store(acc[mi][ni][r], orow + ni * 16);
            }
        }
}

extern "C" void kernel_launch(void* const* d_in, const int* in_sizes, int n_in,
                              void* d_out, int out_size, void* d_ws, size_t ws_size,
                              hipStream_t stream) {
    const float* x      = (const float*)d_in[0];
    const int*   groups = (const int*)d_in[1];
    const float* Wb     = (const float*)d_in[2];
    const float* WA     = (const float*)d_in[3];
    const float* WB     = (const float*)d_in[4];
    float* out = (float*)d_out;

    char* ws = (char*)d_ws;
    int*   starts = (int*)ws;                                             // 36 B
    short* xb     = (short*)(ws + 1024);                                  // 16 MB
    short* Wt     = (short*)(ws + 1024 + (size_t)16 * 1024 * 1024);       // 16 MB

    hipLaunchKernelGGL(prep_kernel, dim3(PREP_GRID), dim3(256), 0, stream,
                       x, Wb, WA, WB, groups, xb, Wt, starts);
    hipLaunchKernelGGL(gemm_grouped, dim3(GRID), dim3(256), 0, stream,
                       xb, Wt, starts, out);
}